// Round 13
// baseline (133.770 us; speedup 1.0000x reference)
//
#include <hip/hip_runtime.h>
#include <hip/hip_bf16.h>
#include <math.h>

constexpr int B_  = 2048;
constexpr int S_  = 16;
constexpr int D_  = 512;
constexpr int CH_ = 1024;

typedef __attribute__((ext_vector_type(8))) short bf16x8;
typedef __attribute__((ext_vector_type(4))) float f32x4;

// ---------------- workspace layout ----------------
constexpr size_t CNT_OFF  = 0;                                  // 16 ints (64 B)
constexpr size_t DONE_OFF = 64;                                 // 1 int
constexpr size_t NT_OFF   = 96;                                 // 1 int
constexpr size_t TL_OFF   = 128;                                // 64 ints
constexpr size_t LIST_OFF = 512;                                // 16*2048 ints = 128 KB
constexpr size_t XGT_OFF  = LIST_OFF + (size_t)16 * 2048 * 4;   // 2 MB bf16 [B][D]
constexpr size_t XGR_OFF  = XGT_OFF + (size_t)B_ * D_ * 2;      // 2 MB bf16 [B][D]

static __device__ __forceinline__ short f2bf(float x) {
    __hip_bfloat16 h = __float2bfloat16(x);
    return *(short*)&h;
}
static __device__ __forceinline__ float gelu_exact(float x) {
    return 0.5f * x * (1.f + erff(x * 0.70710678118654752f));
}
static __device__ __forceinline__ float dot4(float4 a, float4 b) {
    return a.x * b.x + a.y * b.y + a.z * b.z + a.w * b.w;
}

// async global -> LDS, 16 bytes per lane (per-lane global src, wave-uniform LDS base + lane*16)
static __device__ __forceinline__ void gl_lds16(const void* g, void* l) {
    __builtin_amdgcn_global_load_lds(
        (const __attribute__((address_space(1))) void*)g,
        (__attribute__((address_space(3))) void*)l,
        16, 0, 0);
}

// ---------------- kernel 1: fused router (DMA-staged) + inline tile-list tail ----------------
// one sample per block; 64 KB LDS slab staged by 32+32 async 1KB DMAs
__global__ __launch_bounds__(256, 2) void k_router(
    const float* __restrict__ ldt, const float* __restrict__ ldr,
    const float* __restrict__ w,   const float* __restrict__ bsc,
    float* __restrict__ sld, int* __restrict__ count, int* __restrict__ list,
    unsigned short* __restrict__ xgt, unsigned short* __restrict__ xgr,
    float* __restrict__ pose, int* __restrict__ done,
    int* __restrict__ ntile, int* __restrict__ tlist)
{
    const int b    = blockIdx.x;
    const int tid  = threadIdx.x;
    const int wave = tid >> 6;
    const int lane = tid & 63;

    __shared__ float Xs[16384];    // 64 KB: [0,8192) = t slab, [8192,16384) = r slab
    __shared__ float lgs[S_];
    __shared__ int   smi;

    // ---- fire all DMA stages (16 per wave, 1 KB each) ----
    const float* srct = ldt + (size_t)b * S_ * D_;
    const float* srcr = ldr + (size_t)b * S_ * D_;
    #pragma unroll
    for (int i = 0; i < 8; i++) {
        const int inst = wave * 8 + i;             // 0..31
        gl_lds16(srct + inst * 256 + lane * 4, &Xs[inst * 256]);
        gl_lds16(srcr + inst * 256 + lane * 4, &Xs[8192 + inst * 256]);
    }

    // overlap: pose zeroing + router weights into registers
    if (tid < 7) pose[(size_t)b * 7 + tid] = 0.f;
    const float4* wt = (const float4*)w;
    const float4 wv0 = wt[lane];
    const float4 wv1 = wt[lane + 64];
    const float4 wv2 = wt[lane + 128];
    const float4 wv3 = wt[lane + 192];
    const float bias = bsc[0];

    __syncthreads();   // vmcnt(0) drain: slab resident

    // ---- logits: wave w handles scenes 4w..4w+3 ----
    #pragma unroll
    for (int it = 0; it < 4; it++) {
        const int s = wave * 4 + it;
        const float4 a0 = *(const float4*)&Xs[s * 512 + lane * 4];
        const float4 a1 = *(const float4*)&Xs[s * 512 + 256 + lane * 4];
        const float4 c0 = *(const float4*)&Xs[8192 + s * 512 + lane * 4];
        const float4 c1 = *(const float4*)&Xs[8192 + s * 512 + 256 + lane * 4];
        float a = dot4(a0, wv0) + dot4(a1, wv1) + dot4(c0, wv2) + dot4(c1, wv3);
        #pragma unroll
        for (int off = 32; off > 0; off >>= 1) a += __shfl_down(a, off, 64);
        if (lane == 0) lgs[s] = a + bias;
    }
    __syncthreads();

    // ---- softmax + argmax + compaction (threads 0..15) ----
    if (tid < S_) {
        const float v = lgs[tid];
        float mv = v; int mi_ = tid;
        #pragma unroll
        for (int d = 1; d < 16; d <<= 1) {
            float ov = __shfl_xor(mv, d, 16);
            int   oi = __shfl_xor(mi_, d, 16);
            if (ov > mv || (ov == mv && oi < mi_)) { mv = ov; mi_ = oi; }
        }
        float sum = expf(v - mv);
        #pragma unroll
        for (int d = 1; d < 16; d <<= 1) sum += __shfl_xor(sum, d, 16);
        sld[b * S_ + tid] = v - (mv + logf(sum));
        if (tid == 0) {
            smi = mi_;
            const int pos = atomicAdd(&count[mi_], 1);
            list[mi_ * B_ + pos] = b;
        }
    }
    __syncthreads();

    // ---- gather selected rows from LDS -> compact bf16 ----
    const int mi = smi;
    if (tid < 128) {
        const float4 v = *(const float4*)&Xs[mi * 512 + tid * 4];
        short4 o; o.x = f2bf(v.x); o.y = f2bf(v.y); o.z = f2bf(v.z); o.w = f2bf(v.w);
        *reinterpret_cast<short4*>(&xgt[(size_t)b * D_ + (size_t)tid * 4]) = o;
    } else {
        const int t2 = tid - 128;
        const float4 v = *(const float4*)&Xs[8192 + mi * 512 + t2 * 4];
        short4 o; o.x = f2bf(v.x); o.y = f2bf(v.y); o.z = f2bf(v.z); o.w = f2bf(v.w);
        *reinterpret_cast<short4*>(&xgr[(size_t)b * D_ + (size_t)t2 * 4]) = o;
    }

    // ---- last-finishing block builds the compact tile list (replaces k_tiles) ----
    if (tid == 0) {
        __threadfence();
        if (atomicAdd(done, 1) == (int)gridDim.x - 1) {
            int nt = 0;
            for (int mm = 0; mm < S_; mm++) {
                const int c = atomicAdd(&count[mm], 0);   // coherent read
                const int nst = (c + 63) >> 6;
                for (int s2 = 0; s2 < nst; s2++) tlist[nt++] = mm | (s2 << 8);
            }
            ntile[0] = nt;
        }
    }
}

// ---------------- kernel 2: expert heads — global_load_lds staged MFMA ----------------
// bid = t(6) | head(1) | ct(4);  BM=64 x BN=64 x BK=64, 8 K-tiles
__global__ __launch_bounds__(256) void k_expert(
    const float* __restrict__ Wht, const float* __restrict__ bht,
    const float* __restrict__ Wot, const float* __restrict__ bot,
    const float* __restrict__ Whr, const float* __restrict__ bhr,
    const float* __restrict__ Wor, const float* __restrict__ bor,
    const unsigned short* __restrict__ xgt, const unsigned short* __restrict__ xgr,
    const int* __restrict__ count, const int* __restrict__ list,
    const int* __restrict__ ntile, const int* __restrict__ tlist,
    float* __restrict__ pose)
{
    const int bid  = blockIdx.x;
    const int ct   = bid & 15;
    const int head = (bid >> 4) & 1;
    const int t    = bid >> 5;
    if (t >= ntile[0]) return;
    const int tv = tlist[t];
    const int m  = tv & 255;
    const int st = tv >> 8;
    const int n  = count[m];

    const unsigned short* __restrict__ xg = head ? xgr : xgt;
    const float* __restrict__ Wh = head ? Whr : Wht;
    const float* __restrict__ bh = head ? bhr : bht;
    const float* __restrict__ Wo = head ? Wor : Wot;
    const float* __restrict__ bo = head ? bor : bot;
    const int noj    = head ? 4 : 3;
    const int jobase = head ? 3 : 0;
    const int ch0    = ct * 64;

    __shared__ short As[64 * 64];    //  8 KB bf16, source-swizzled k-chunks
    __shared__ float Bsf[64 * 64];   // 16 KB f32 linear [k][ch]
    __shared__ float ored[64][4];    //  1 KB
    __shared__ int   bidx[64];

    const int tid  = threadIdx.x;
    const int wave = tid >> 6;
    const int lane = tid & 63;
    const int l15  = lane & 15;
    const int lq   = lane >> 4;
    const int wr   = wave >> 1, wc = wave & 1;
    const int rbase = wr * 32, cbase = wc * 32;

    if (tid < 64) {
        const int gi = st * 64 + tid;
        bidx[tid] = (gi < n) ? list[m * B_ + gi] : list[m * B_];
    }
    ((float*)ored)[tid] = 0.f;
    __syncthreads();

    const unsigned short* gA[2];
    #pragma unroll
    for (int i = 0; i < 2; i++) {
        const int r = (wave * 2 + i) * 8 + (lane >> 3);
        const int c = (lane & 7) ^ (r & 7);
        gA[i] = xg + (size_t)bidx[r] * D_ + c * 8;
    }
    const float* gB[4];
    #pragma unroll
    for (int i = 0; i < 4; i++) {
        const int q2 = wave * 4 + i;
        gB[i] = Wh + (size_t)m * D_ * CH_ + (size_t)(q2 * 4 + (lane >> 4)) * CH_ + ch0 + (l15 * 4);
    }

    f32x4 acc[2][2] = {};

    for (int kt = 0; kt < 8; kt++) {
        const int k0 = kt * 64;
        #pragma unroll
        for (int i = 0; i < 2; i++)
            gl_lds16(gA[i] + k0, &As[(wave * 2 + i) * 512]);
        #pragma unroll
        for (int i = 0; i < 4; i++)
            gl_lds16(gB[i] + (size_t)k0 * CH_, &Bsf[(wave * 4 + i) * 256]);
        __syncthreads();

        #pragma unroll
        for (int ks = 0; ks < 2; ks++) {
            bf16x8 a[2];
            #pragma unroll
            for (int fm = 0; fm < 2; fm++) {
                const int r = rbase + fm * 16 + l15;
                const int u = ks * 4 + lq;
                a[fm] = *(const bf16x8*)&As[r * 64 + ((u ^ (r & 7)) << 3)];
            }
            bf16x8 bv[2];
            #pragma unroll
            for (int fn = 0; fn < 2; fn++) {
                const int c = cbase + fn * 16 + l15;
                const int kb = ks * 32 + lq * 8;
                short tmp[8];
                #pragma unroll
                for (int j = 0; j < 8; j++) tmp[j] = f2bf(Bsf[(kb + j) * 64 + c]);
                bv[fn] = *(bf16x8*)tmp;
            }
            #pragma unroll
            for (int fm = 0; fm < 2; fm++)
                #pragma unroll
                for (int fn = 0; fn < 2; fn++)
                    acc[fm][fn] = __builtin_amdgcn_mfma_f32_16x16x32_bf16(a[fm], bv[fn], acc[fm][fn], 0, 0, 0);
        }
        __syncthreads();
    }

    // ---- epilogue ----
    float g[2][2][4];
    float wo_l[2][4];
    #pragma unroll
    for (int fn = 0; fn < 2; fn++) {
        const int ch = ch0 + cbase + fn * 16 + l15;
        const float bias = bh[m * CH_ + ch];
        #pragma unroll
        for (int fm = 0; fm < 2; fm++)
            #pragma unroll
            for (int j = 0; j < 4; j++)
                g[fm][fn][j] = gelu_exact(acc[fm][fn][j] + bias);
        #pragma unroll
        for (int jo = 0; jo < 4; jo++)
            wo_l[fn][jo] = (jo < noj) ? Wo[(size_t)(m * CH_ + ch) * noj + jo] : 0.f;
    }

    #pragma unroll
    for (int fm = 0; fm < 2; fm++) {
        #pragma unroll
        for (int j = 0; j < 4; j++) {
            const int rl = rbase + fm * 16 + lq * 4 + j;
            #pragma unroll
            for (int jo = 0; jo < 4; jo++) {
                if (jo >= noj) continue;
                float v = g[fm][0][j] * wo_l[0][jo] + g[fm][1][j] * wo_l[1][jo];
                #pragma unroll
                for (int d = 1; d < 16; d <<= 1) v += __shfl_xor(v, d, 16);
                if (l15 == 0)
                    atomicAdd(&ored[rl][jo], v);
            }
        }
    }
    __syncthreads();

    {
        const int rl = tid >> 2;
        const int jo = tid & 3;
        const int gi = st * 64 + rl;
        if (jo < noj && gi < n) {
            const int bb = list[m * B_ + gi];
            float v = ored[rl][jo];
            if (ct == 0) v += bo[m * noj + jo];
            atomicAdd(&pose[(size_t)bb * 7 + jobase + jo], v);
        }
    }
}

// ---------------- launch ----------------
extern "C" void kernel_launch(void* const* d_in, const int* in_sizes, int n_in,
                              void* d_out, int out_size, void* d_ws, size_t ws_size,
                              hipStream_t stream)
{
    const float* ldt = (const float*)d_in[0];
    const float* ldr = (const float*)d_in[1];
    const float* wsc = (const float*)d_in[2];
    const float* bsc = (const float*)d_in[3];
    const float* Wht = (const float*)d_in[4];
    const float* bht = (const float*)d_in[5];
    const float* Wot = (const float*)d_in[6];
    const float* bot = (const float*)d_in[7];
    const float* Whr = (const float*)d_in[8];
    const float* bhr = (const float*)d_in[9];
    const float* Wor = (const float*)d_in[10];
    const float* bor = (const float*)d_in[11];

    float* pose = (float*)d_out;                   // [B,7]
    float* sld  = (float*)d_out + (size_t)B_ * 7;  // [B,16]

    int* count = (int*)((char*)d_ws + CNT_OFF);
    int* done  = (int*)((char*)d_ws + DONE_OFF);
    int* ntile = (int*)((char*)d_ws + NT_OFF);
    int* tlist = (int*)((char*)d_ws + TL_OFF);
    int* list  = (int*)((char*)d_ws + LIST_OFF);
    unsigned short* xgt = (unsigned short*)((char*)d_ws + XGT_OFF);
    unsigned short* xgr = (unsigned short*)((char*)d_ws + XGR_OFF);

    (void)hipMemsetAsync(d_ws, 0, 128, stream);   // count + done + ntile

    // 1) fused router: one sample per block, DMA-staged 64 KB slab; tail builds tile list
    k_router<<<dim3(B_), dim3(256), 0, stream>>>(
        ldt, ldr, wsc, bsc, sld, count, list, xgt, xgr, pose, done, ntile, tlist);

    // 2) expert heads: grid = 48 tile slots x 2 heads x 16 ch-stripes
    k_expert<<<dim3(48 * 2 * 16), dim3(256), 0, stream>>>(
        Wht, bht, Wot, bot, Whr, bhr, Wor, bor,
        xgt, xgr, count, list, ntile, tlist, pose);
}

// Round 14
// 74.881 us; speedup vs baseline: 1.7864x; 1.7864x over previous
//
#include <hip/hip_runtime.h>
#include <hip/hip_bf16.h>
#include <math.h>

constexpr int B_  = 2048;
constexpr int S_  = 16;
constexpr int D_  = 512;
constexpr int CH_ = 1024;

typedef __attribute__((ext_vector_type(8))) short bf16x8;
typedef __attribute__((ext_vector_type(4))) float f32x4;

// ---------------- workspace layout ----------------
constexpr size_t CNT_OFF  = 0;                                  // 16 ints (64 B)
constexpr size_t LIST_OFF = 512;                                // 16*2048 ints = 128 KB
constexpr size_t XGT_OFF  = LIST_OFF + (size_t)16 * 2048 * 4;   // 2 MB bf16 [B][D]
constexpr size_t XGR_OFF  = XGT_OFF + (size_t)B_ * D_ * 2;      // 2 MB bf16 [B][D]

static __device__ __forceinline__ short f2bf(float x) {
    __hip_bfloat16 h = __float2bfloat16(x);
    return *(short*)&h;
}
static __device__ __forceinline__ float gelu_exact(float x) {
    return 0.5f * x * (1.f + erff(x * 0.70710678118654752f));
}

// async global -> LDS, 16 bytes per lane
static __device__ __forceinline__ void gl_lds16(const void* g, void* l) {
    __builtin_amdgcn_global_load_lds(
        (const __attribute__((address_space(1))) void*)g,
        (__attribute__((address_space(3))) void*)l,
        16, 0, 0);
}

// ---------------- kernel 1: router + log_softmax + argmax + compaction + x gather ----------------
// one sample per block; 16 waves, one scene per wave  (round-8 champion, unchanged)
__global__ __launch_bounds__(1024) void k_router_sm(
    const float* __restrict__ ldt, const float* __restrict__ ldr,
    const float* __restrict__ w,   const float* __restrict__ bsc,
    float* __restrict__ sld, int* __restrict__ count, int* __restrict__ list,
    unsigned short* __restrict__ xgt, unsigned short* __restrict__ xgr,
    float* __restrict__ pose)
{
    const int b    = blockIdx.x;
    const int wave = threadIdx.x >> 6;
    const int lane = threadIdx.x & 63;

    __shared__ float lgs[S_];
    __shared__ int   smi;

    if (threadIdx.x < 7) pose[(size_t)b * 7 + threadIdx.x] = 0.f;

    const float4* pt = (const float4*)(ldt + ((size_t)b * S_ + wave) * D_);
    const float4* pr = (const float4*)(ldr + ((size_t)b * S_ + wave) * D_);
    const float4* wt = (const float4*)(w);
    const float4* wr = (const float4*)(w + D_);

    float acc = 0.f;
    #pragma unroll
    for (int it = 0; it < 2; it++) {
        const int i = lane + it * 64;
        float4 a  = pt[i]; float4 ww = wt[i];
        acc += a.x * ww.x + a.y * ww.y + a.z * ww.z + a.w * ww.w;
        float4 c  = pr[i]; float4 w2 = wr[i];
        acc += c.x * w2.x + c.y * w2.y + c.z * w2.z + c.w * w2.w;
    }
    #pragma unroll
    for (int off = 32; off > 0; off >>= 1) acc += __shfl_down(acc, off, 64);
    if (lane == 0) lgs[wave] = acc;
    __syncthreads();

    if (threadIdx.x < S_) {
        const int s = threadIdx.x;
        const float v = lgs[s] + bsc[0];
        float mv = v; int mi = s;
        #pragma unroll
        for (int d = 1; d < 16; d <<= 1) {
            float ov = __shfl_xor(mv, d, 16);
            int   oi = __shfl_xor(mi, d, 16);
            if (ov > mv || (ov == mv && oi < mi)) { mv = ov; mi = oi; }
        }
        float sum = expf(v - mv);
        #pragma unroll
        for (int d = 1; d < 16; d <<= 1) sum += __shfl_xor(sum, d, 16);
        const float lse = mv + logf(sum);
        sld[b * S_ + s] = v - lse;
        if (s == 0) {
            smi = mi;
            const int pos = atomicAdd(&count[mi], 1);
            list[mi * B_ + pos] = b;
        }
    }
    __syncthreads();

    const int mi = smi;
    const int t = threadIdx.x;
    if (t < D_) {
        xgt[(size_t)b * D_ + t] = (unsigned short)f2bf(ldt[((size_t)b * S_ + mi) * D_ + t]);
    } else {
        const int t2 = t - D_;
        xgr[(size_t)b * D_ + t2] = (unsigned short)f2bf(ldr[((size_t)b * S_ + mi) * D_ + t2]);
    }
}

// ---------------- kernel 2: expert heads — global_load_lds staged MFMA ----------------
// bid = t(6) | head(1) | ct(4); (m, st) decoded from count[] in-block (no tile list)
__global__ __launch_bounds__(256) void k_expert(
    const float* __restrict__ Wht, const float* __restrict__ bht,
    const float* __restrict__ Wot, const float* __restrict__ bot,
    const float* __restrict__ Whr, const float* __restrict__ bhr,
    const float* __restrict__ Wor, const float* __restrict__ bor,
    const unsigned short* __restrict__ xgt, const unsigned short* __restrict__ xgr,
    const int* __restrict__ count, const int* __restrict__ list,
    float* __restrict__ pose)
{
    const int bid  = blockIdx.x;
    const int ct   = bid & 15;
    const int head = (bid >> 4) & 1;
    const int t    = bid >> 5;

    // decode tile t -> (m, st) by prefix-scanning ceil(count[m]/64)
    int m = 0, base = 0;
    int n = 0;
    for (; m < S_; m++) {
        n = count[m];
        const int nst = (n + 63) >> 6;
        if (t < base + nst) break;
        base += nst;
    }
    if (m == S_) return;           // t beyond total tiles
    const int st = t - base;

    const unsigned short* __restrict__ xg = head ? xgr : xgt;
    const float* __restrict__ Wh = head ? Whr : Wht;
    const float* __restrict__ bh = head ? bhr : bht;
    const float* __restrict__ Wo = head ? Wor : Wot;
    const float* __restrict__ bo = head ? bor : bot;
    const int noj    = head ? 4 : 3;
    const int jobase = head ? 3 : 0;
    const int ch0    = ct * 64;

    __shared__ short As[64 * 64];    //  8 KB bf16, source-swizzled k-chunks
    __shared__ float Bsf[64 * 64];   // 16 KB f32 linear [k][ch]
    __shared__ float ored[64][4];    //  1 KB
    __shared__ int   bidx[64];

    const int tid  = threadIdx.x;
    const int wave = tid >> 6;
    const int lane = tid & 63;
    const int l15  = lane & 15;
    const int lq   = lane >> 4;
    const int wr   = wave >> 1, wc = wave & 1;
    const int rbase = wr * 32, cbase = wc * 32;

    if (tid < 64) {
        const int gi = st * 64 + tid;
        bidx[tid] = (gi < n) ? list[m * B_ + gi] : list[m * B_];
    }
    ((float*)ored)[tid] = 0.f;
    __syncthreads();

    const unsigned short* gA[2];
    #pragma unroll
    for (int i = 0; i < 2; i++) {
        const int r = (wave * 2 + i) * 8 + (lane >> 3);
        const int c = (lane & 7) ^ (r & 7);
        gA[i] = xg + (size_t)bidx[r] * D_ + c * 8;
    }
    const float* gB[4];
    #pragma unroll
    for (int i = 0; i < 4; i++) {
        const int q2 = wave * 4 + i;
        gB[i] = Wh + (size_t)m * D_ * CH_ + (size_t)(q2 * 4 + (lane >> 4)) * CH_ + ch0 + (l15 * 4);
    }

    f32x4 acc[2][2] = {};

    for (int kt = 0; kt < 8; kt++) {
        const int k0 = kt * 64;
        #pragma unroll
        for (int i = 0; i < 2; i++)
            gl_lds16(gA[i] + k0, &As[(wave * 2 + i) * 512]);
        #pragma unroll
        for (int i = 0; i < 4; i++)
            gl_lds16(gB[i] + (size_t)k0 * CH_, &Bsf[(wave * 4 + i) * 256]);
        __syncthreads();

        #pragma unroll
        for (int ks = 0; ks < 2; ks++) {
            bf16x8 a[2];
            #pragma unroll
            for (int fm = 0; fm < 2; fm++) {
                const int r = rbase + fm * 16 + l15;
                const int u = ks * 4 + lq;
                a[fm] = *(const bf16x8*)&As[r * 64 + ((u ^ (r & 7)) << 3)];
            }
            bf16x8 bv[2];
            #pragma unroll
            for (int fn = 0; fn < 2; fn++) {
                const int c = cbase + fn * 16 + l15;
                const int kb = ks * 32 + lq * 8;
                short tmp[8];
                #pragma unroll
                for (int j = 0; j < 8; j++) tmp[j] = f2bf(Bsf[(kb + j) * 64 + c]);
                bv[fn] = *(bf16x8*)tmp;
            }
            #pragma unroll
            for (int fm = 0; fm < 2; fm++)
                #pragma unroll
                for (int fn = 0; fn < 2; fn++)
                    acc[fm][fn] = __builtin_amdgcn_mfma_f32_16x16x32_bf16(a[fm], bv[fn], acc[fm][fn], 0, 0, 0);
        }
        __syncthreads();
    }

    // ---- epilogue: bias + GELU + Wo partial, 16-lane reduce, LDS combine ----
    float g[2][2][4];
    float wo_l[2][4];
    #pragma unroll
    for (int fn = 0; fn < 2; fn++) {
        const int ch = ch0 + cbase + fn * 16 + l15;
        const float bias = bh[m * CH_ + ch];
        #pragma unroll
        for (int fm = 0; fm < 2; fm++)
            #pragma unroll
            for (int j = 0; j < 4; j++)
                g[fm][fn][j] = gelu_exact(acc[fm][fn][j] + bias);
        #pragma unroll
        for (int jo = 0; jo < 4; jo++)
            wo_l[fn][jo] = (jo < noj) ? Wo[(size_t)(m * CH_ + ch) * noj + jo] : 0.f;
    }

    #pragma unroll
    for (int fm = 0; fm < 2; fm++) {
        #pragma unroll
        for (int j = 0; j < 4; j++) {
            const int rl = rbase + fm * 16 + lq * 4 + j;
            #pragma unroll
            for (int jo = 0; jo < 4; jo++) {
                if (jo >= noj) continue;
                float v = g[fm][0][j] * wo_l[0][jo] + g[fm][1][j] * wo_l[1][jo];
                #pragma unroll
                for (int d = 1; d < 16; d <<= 1) v += __shfl_xor(v, d, 16);
                if (l15 == 0)
                    atomicAdd(&ored[rl][jo], v);
            }
        }
    }
    __syncthreads();

    {
        const int rl = tid >> 2;
        const int jo = tid & 3;
        const int gi = st * 64 + rl;
        if (jo < noj && gi < n) {
            const int bb = list[m * B_ + gi];
            float v = ored[rl][jo];
            if (ct == 0) v += bo[m * noj + jo];
            atomicAdd(&pose[(size_t)bb * 7 + jobase + jo], v);
        }
    }
}

// ---------------- launch ----------------
extern "C" void kernel_launch(void* const* d_in, const int* in_sizes, int n_in,
                              void* d_out, int out_size, void* d_ws, size_t ws_size,
                              hipStream_t stream)
{
    const float* ldt = (const float*)d_in[0];
    const float* ldr = (const float*)d_in[1];
    const float* wsc = (const float*)d_in[2];
    const float* bsc = (const float*)d_in[3];
    const float* Wht = (const float*)d_in[4];
    const float* bht = (const float*)d_in[5];
    const float* Wot = (const float*)d_in[6];
    const float* bot = (const float*)d_in[7];
    const float* Whr = (const float*)d_in[8];
    const float* bhr = (const float*)d_in[9];
    const float* Wor = (const float*)d_in[10];
    const float* bor = (const float*)d_in[11];

    float* pose = (float*)d_out;                   // [B,7]
    float* sld  = (float*)d_out + (size_t)B_ * 7;  // [B,16]

    int* count = (int*)((char*)d_ws + CNT_OFF);
    int* list  = (int*)((char*)d_ws + LIST_OFF);
    unsigned short* xgt = (unsigned short*)((char*)d_ws + XGT_OFF);
    unsigned short* xgr = (unsigned short*)((char*)d_ws + XGR_OFF);

    (void)hipMemsetAsync(count, 0, 16 * sizeof(int), stream);

    // 1) router + softmax + argmax + compaction + bf16 gather (+ pose zeroing)
    k_router_sm<<<dim3(B_), dim3(1024), 0, stream>>>(
        ldt, ldr, wsc, bsc, sld, count, list, xgt, xgr, pose);

    // 2) expert heads: grid = 48 tile slots x 2 heads x 16 ch-stripes; (m,st) decoded in-block
    k_expert<<<dim3(48 * 2 * 16), dim3(256), 0, stream>>>(
        Wht, bht, Wot, bot, Whr, bhr, Wor, bor,
        xgt, xgr, count, list, pose);
}